// Round 6
// baseline (1664.478 us; speedup 1.0000x reference)
//
#include <hip/hip_runtime.h>
#include <hip/hip_bf16.h>
#include <hip/hip_fp16.h>
#include <math.h>

#define EPSV 1e-5f

typedef short short8 __attribute__((ext_vector_type(8)));
typedef float f32x4 __attribute__((ext_vector_type(4)));
typedef unsigned long long u64;

#define MFMA(a, b, c) __builtin_amdgcn_mfma_f32_16x16x32_f16(a, b, c, 0, 0, 0)

// ---------------- ws layout (bytes) ----------------
#define OFF_SC1    8192            // 64 f32
#define OFF_SH1    8448
#define OFF_SC2    8704            // 128 f32
#define OFF_SH2    9216
#define OFF_B0     9728            // 1024 f32 = 4096
#define OFF_B1     13824           // 4096
#define OFF_PART1  17920           // 256*64*2*4 = 131072
#define OFF_PART2  148992          // 256*128*2*4 = 262144
#define OFF_W2F    411136          // 40960 f16 = 81920
#define OFF_WF     493056          // 917504 f16 = 1835008
#define OFF_SEQ    2328064         // 256*256*128*2 = 16777216 (f16 [b][t][c])
#define OFF_H0W    19105280       // 2*256*128*8 = 524288 (tagged u64 words)
#define OFF_H1W    19629568       // 524288
#define OFF_HF     20153856       // 256*256*4 = 262144 (f32)
// end 20,416,000

__device__ __forceinline__ unsigned short f2h(float f) {
  return __half_as_ushort(__float2half(f));
}
__device__ __forceinline__ float h2f(unsigned short u) {
  return __half2float(__ushort_as_half(u));
}
__device__ __forceinline__ float sigf(float x) { return 1.f / (1.f + __expf(-x)); }
__device__ __forceinline__ float tanhfast(float x) {
  return 1.f - 2.f / (__expf(2.f * x) + 1.f);
}

// ---------------- init: zero tagged h word buffers (1 MB) ----------------
__global__ void k_init(u64* hz) {
  hz[blockIdx.x * 256 + threadIdx.x] = 0ULL;  // grid 512 -> 131072 u64
}

// ---------------- conv1 + relu + pool4, BN1 partial stats ----------------
__global__ __launch_bounds__(256, 2) void k_conv1(const float* __restrict__ x,
                                                  const float* __restrict__ w1,
                                                  const float* __restrict__ b1,
                                                  float* __restrict__ part1) {
  __shared__ float xs[4104];
  __shared__ float w1s[576];
  __shared__ float b1s[64];
  __shared__ float red[64][4][2];
  const int tid = threadIdx.x, b = blockIdx.x;
  for (int j = tid; j < 4104; j += 256) {
    int p = j - 4;
    xs[j] = (p >= 0 && p < 4096) ? x[b * 4096 + p] : 0.f;
  }
  for (int j = tid; j < 576; j += 256) w1s[j] = w1[j];
  if (tid < 64) b1s[tid] = b1[tid];
  __syncthreads();
  const int c = tid >> 2, lq = tid & 3;
  float wr[9];
#pragma unroll
  for (int k = 0; k < 9; k++) wr[k] = w1s[c * 9 + k];
  const float bb = b1s[c];
  float S = 0.f, SS = 0.f;
  for (int li = 0; li < 256; li++) {
    int l = lq * 256 + li;
    int base = 4 * l;
    float a4 = 0.f;
#pragma unroll
    for (int jj = 0; jj < 4; jj++) {
      float cv = bb;
#pragma unroll
      for (int k = 0; k < 9; k++) cv += xs[base + jj + k] * wr[k];
      a4 += fmaxf(cv, 0.f);
    }
    float y = 0.25f * a4;
    S += y;
    SS += y * y;
  }
  red[c][lq][0] = S;
  red[c][lq][1] = SS;
  __syncthreads();
  if (tid < 64) {
    float s = 0.f, ss = 0.f;
#pragma unroll
    for (int q = 0; q < 4; q++) {
      s += red[tid][q][0];
      ss += red[tid][q][1];
    }
    part1[(b * 64 + tid) * 2 + 0] = s;
    part1[(b * 64 + tid) * 2 + 1] = ss;
  }
}

// ---------------- BN1 finalize ----------------
__global__ void k_bn1(const float* __restrict__ part1, const float* __restrict__ g,
                      const float* __restrict__ bt, float* __restrict__ sc,
                      float* __restrict__ sh) {
  __shared__ float rs[256], rss[256];
  const int c = blockIdx.x, tid = threadIdx.x;
  rs[tid] = part1[(tid * 64 + c) * 2 + 0];
  rss[tid] = part1[(tid * 64 + c) * 2 + 1];
  __syncthreads();
  for (int st = 128; st > 0; st >>= 1) {
    if (tid < st) {
      rs[tid] += rs[tid + st];
      rss[tid] += rss[tid + st];
    }
    __syncthreads();
  }
  if (tid == 0) {
    const float N = 256.f * 1024.f;
    float mean = rs[0] / N;
    float var = rss[0] / N - mean * mean;
    float scale = g[c] * rsqrtf(var + EPSV);
    sc[c] = scale;
    sh[c] = bt[c] - mean * scale;
  }
}

// ---------------- w2 -> MFMA B-fragment layout (f16) ----------------
__global__ void k_w2frag(const float* __restrict__ w2,
                         unsigned short* __restrict__ w2f) {
  int n = blockIdx.x * 256 + threadIdx.x;  // < 40960
  if (n >= 40960) return;
  int e = n & 7, lane = (n >> 3) & 63, ot = (n >> 9) & 7, sc = n >> 12;
  int s = sc >> 1, c2 = sc & 1;
  int o = ot * 16 + (lane & 15);
  int i = c2 * 32 + ((lane >> 4) << 3) + e;
  w2f[n] = f2h(w2[o * 320 + i * 5 + s]);
}

// ---------------- conv2 via MFMA (recomputes conv1+bn1 into LDS y1t) -------
__global__ __launch_bounds__(256, 1) void k_conv2(
    const float* __restrict__ x, const float* __restrict__ w1,
    const float* __restrict__ b1, const float* __restrict__ sc1,
    const float* __restrict__ sh1, const unsigned short* __restrict__ w2f,
    const float* __restrict__ b2, unsigned short* __restrict__ seq,
    float* __restrict__ part2) {
  __shared__ float xs[4104];
  __shared__ unsigned short y1t[1028][66];  // row = l+2, col = i
  __shared__ float w1s[576], b1s[64], s1s[64], h1s[64], b2s[128];
  __shared__ float red[4][2][128];
  const int tid = threadIdx.x, b = blockIdx.x;
  for (int j = tid; j < 4104; j += 256) {
    int p = j - 4;
    xs[j] = (p >= 0 && p < 4096) ? x[b * 4096 + p] : 0.f;
  }
  for (int j = tid; j < 576; j += 256) w1s[j] = w1[j];
  if (tid < 64) {
    b1s[tid] = b1[tid];
    s1s[tid] = sc1[tid];
    h1s[tid] = sh1[tid];
  }
  if (tid < 128) b2s[tid] = b2[tid];
  if (tid < 132) {
    int r4 = tid / 33, c4 = tid % 33;
    int row = (r4 < 2) ? r4 : (1024 + r4);
    ((unsigned int*)&y1t[row][0])[c4] = 0u;
  }
  __syncthreads();
  {
    const int i2 = tid & 31, lg = tid >> 5;
    const int ia = 2 * i2, ib = ia + 1;
    float wra[9], wrb[9];
#pragma unroll
    for (int k = 0; k < 9; k++) {
      wra[k] = w1s[ia * 9 + k];
      wrb[k] = w1s[ib * 9 + k];
    }
    const float bia = b1s[ia], bib = b1s[ib];
    const float sa = s1s[ia], sb = s1s[ib], ha = h1s[ia], hb = h1s[ib];
    for (int j = 0; j < 128; j++) {
      int l = lg * 128 + j;
      float xv[12];
#pragma unroll
      for (int m = 0; m < 12; m++) xv[m] = xs[4 * l + m];
      float aa = 0.f, ab = 0.f;
#pragma unroll
      for (int jj = 0; jj < 4; jj++) {
        float ca = bia, cb = bib;
#pragma unroll
        for (int k = 0; k < 9; k++) {
          float xx = xv[jj + k];
          ca += xx * wra[k];
          cb += xx * wrb[k];
        }
        aa += fmaxf(ca, 0.f);
        ab += fmaxf(cb, 0.f);
      }
      float va = 0.25f * aa * sa + ha;
      float vb = 0.25f * ab * sb + hb;
      unsigned int pk = (unsigned int)f2h(va) | ((unsigned int)f2h(vb) << 16);
      *(unsigned int*)&y1t[l + 2][ia] = pk;
    }
  }
  __syncthreads();
  const int wv = tid >> 6, lane = tid & 63;
  const int colo = lane & 15, rq = lane >> 4;
  float Sa[2][4], SSa[2][4];
#pragma unroll
  for (int a = 0; a < 2; a++)
#pragma unroll
    for (int c = 0; c < 4; c++) {
      Sa[a][c] = 0.f;
      SSa[a][c] = 0.f;
    }
#pragma unroll
  for (int og = 0; og < 2; og++) {
    short8 bf[4][10];
#pragma unroll
    for (int ot = 0; ot < 4; ot++)
#pragma unroll
      for (int sc = 0; sc < 10; sc++)
        bf[ot][sc] = *(const short8*)(w2f + ((sc * 8 + og * 4 + ot) * 64 + lane) * 8);
    for (int ltw = 0; ltw < 16; ltw++) {
      int lt = wv * 16 + ltw;
      int lbase = lt * 16;
      short8 af[10];
#pragma unroll
      for (int s = 0; s < 5; s++)
#pragma unroll
        for (int c2 = 0; c2 < 2; c2++)
          af[s * 2 + c2] =
              *(const short8*)&y1t[lbase + colo + s][c2 * 32 + rq * 8];
#pragma unroll
      for (int ot = 0; ot < 4; ot++) {
        f32x4 acc = {0.f, 0.f, 0.f, 0.f};
#pragma unroll
        for (int sc = 0; sc < 10; sc++)
          acc = MFMA(af[sc], bf[ot][sc], acc);
        int o = (og * 4 + ot) * 16 + colo;
        float bv = b2s[o];
        float s4 = fmaxf(acc[0] + bv, 0.f) + fmaxf(acc[1] + bv, 0.f) +
                   fmaxf(acc[2] + bv, 0.f) + fmaxf(acc[3] + bv, 0.f);
        float y = 0.25f * s4;
        int t_out = lt * 4 + rq;
        seq[(b * 256 + t_out) * 128 + o] = f2h(y);
        Sa[og][ot] += y;
        SSa[og][ot] += y * y;
      }
    }
  }
#pragma unroll
  for (int og = 0; og < 2; og++)
#pragma unroll
    for (int ot = 0; ot < 4; ot++) {
      float sv = Sa[og][ot], ssv = SSa[og][ot];
      sv += __shfl_xor(sv, 16, 64);
      sv += __shfl_xor(sv, 32, 64);
      ssv += __shfl_xor(ssv, 16, 64);
      ssv += __shfl_xor(ssv, 32, 64);
      if (rq == 0) {
        int o = (og * 4 + ot) * 16 + colo;
        red[wv][0][o] = sv;
        red[wv][1][o] = ssv;
      }
    }
  __syncthreads();
  if (tid < 128) {
    float s = red[0][0][tid] + red[1][0][tid] + red[2][0][tid] + red[3][0][tid];
    float ss = red[0][1][tid] + red[1][1][tid] + red[2][1][tid] + red[3][1][tid];
    part2[(b * 128 + tid) * 2 + 0] = s;
    part2[(b * 128 + tid) * 2 + 1] = ss;
  }
}

// ---------------- BN2 finalize ----------------
__global__ void k_bn2(const float* __restrict__ part2, const float* __restrict__ g,
                      const float* __restrict__ bt, float* __restrict__ sc,
                      float* __restrict__ sh) {
  __shared__ float rs[256], rss[256];
  const int o = blockIdx.x, tid = threadIdx.x;
  rs[tid] = part2[(tid * 128 + o) * 2 + 0];
  rss[tid] = part2[(tid * 128 + o) * 2 + 1];
  __syncthreads();
  for (int st = 128; st > 0; st >>= 1) {
    if (tid < st) {
      rs[tid] += rs[tid + st];
      rss[tid] += rss[tid + st];
    }
    __syncthreads();
  }
  if (tid == 0) {
    const float N = 65536.f;
    float mean = rs[0] / N;
    float var = rss[0] / N - mean * mean;
    float scale = g[o] * rsqrtf(var + EPSV);
    sc[o] = scale;
    sh[o] = bt[o] - mean * scale;
  }
}

// ---------------- fold BN2 shift into layer-0 bias ----------------
__global__ void k_bias(const float* __restrict__ bi0, const float* __restrict__ bh0,
                       const float* __restrict__ wi0, const float* __restrict__ sh2,
                       const float* __restrict__ bi1, const float* __restrict__ bh1,
                       float* __restrict__ b0arr, float* __restrict__ b1arr) {
  int g = blockIdx.x * 256 + threadIdx.x;  // < 1024
  float s = bi0[g] + bh0[g];
  for (int k = 0; k < 128; k++) s += sh2[k] * wi0[k * 1024 + g];
  b0arr[g] = s;
  b1arr[g] = bi1[g] + bh1[g];
}

// ---------------- LSTM weights -> A-fragment layout (f16, BN2-scaled) -------
__global__ void k_wfrag(const float* __restrict__ wi0, const float* __restrict__ wh0,
                        const float* __restrict__ wi1, const float* __restrict__ wh1,
                        const float* __restrict__ sc2,
                        unsigned short* __restrict__ wf) {
  const int slot = blockIdx.x / 56;
  const int idx = (blockIdx.x % 56) * 256 + threadIdx.x;  // < 14336
  const int j = idx >> 9, lane = (idx >> 3) & 63, e = idx & 7;
  const int sh = slot >> 2, wv = slot & 3;
  const int m = lane & 15;
  const int gcol = (m & 3) * 256 + sh * 16 + wv * 4 + (m >> 2);
  float v;
  if (j < 12) {
    int k = j * 32 + ((lane >> 4) << 3) + e;
    v = (k < 128) ? sc2[k] * wi0[k * 1024 + gcol] : wh0[(k - 128) * 1024 + gcol];
  } else {
    int k = (j - 12) * 32 + ((lane >> 4) << 3) + e;
    v = (k < 256) ? wi1[k * 1024 + gcol] : wh1[(k - 256) * 1024 + gcol];
  }
  wf[slot * 14336 + idx] = f2h(v);
}

// ---------------- persistent 2-layer LSTM, tagged-data rendezvous ----------
// grid 256: gb = blockIdx&15 (batch group, same XCD), sh = blockIdx>>4 (units)
// word (b,p) = [tag:16 | h[2p]:16 | h[2p+1]:16 | 0:16], one u64 atomic
__global__ __launch_bounds__(256, 1) void k_lstm(
    const unsigned short* __restrict__ seq, const unsigned short* __restrict__ wf,
    const float* __restrict__ b0arr, const float* __restrict__ b1arr,
    u64* __restrict__ h0w, u64* __restrict__ h1w, float* __restrict__ hfinal) {
  __shared__ __align__(16) unsigned short hs0[2][16 * 264];
  __shared__ __align__(16) unsigned short hs1[2][16 * 264];
  const int tid = threadIdx.x;
  const int gb = blockIdx.x & 15, sh = blockIdx.x >> 4;
  const int b0 = gb * 16;
  const int wv = tid >> 6, lane = tid & 63;
  const int slot = sh * 4 + wv;
  const int bt = lane & 15;   // batch-local (B-frag col / D col)
  const int ul = lane >> 4;   // unit-local (D row quad)
  const int q8 = ul * 8;
  const int pbase = sh * 8 + wv * 2;  // unit-pair base for this wave

  // --- weight A-fragments in registers, made opaque to block rematerialize --
  f32x4 rw[28];
#pragma unroll
  for (int j = 0; j < 28; j++)
    rw[j] = *(const f32x4*)(wf + ((slot * 28 + j) * 64 + lane) * 8);
#pragma unroll
  for (int j = 0; j < 28; j++) asm volatile("" : "+v"(rw[j]));
#define RW(j) __builtin_bit_cast(short8, rw[j])

  f32x4 b0v, b1v;
#pragma unroll
  for (int r = 0; r < 4; r++) {
    int gcol = r * 256 + sh * 16 + wv * 4 + ul;
    b0v[r] = b0arr[gcol];
    b1v[r] = b1arr[gcol];
  }
  float c0 = 0.f, c1 = 0.f, h1v = 0.f;

  // --- prologue: h0(0) = cell(x(0), c=0); store tagged words (tag 1) ---
  {
    const unsigned short* xp = seq + ((b0 + bt) * 256 + 0) * 128 + q8;
    short8 xa0 = *(const short8*)(xp + 0);
    short8 xa1 = *(const short8*)(xp + 32);
    short8 xa2 = *(const short8*)(xp + 64);
    short8 xa3 = *(const short8*)(xp + 96);
    f32x4 acc = b0v;
    acc = MFMA(RW(0), xa0, acc);
    acc = MFMA(RW(1), xa1, acc);
    acc = MFMA(RW(2), xa2, acc);
    acc = MFMA(RW(3), xa3, acc);
    c0 = sigf(acc[1]) * c0 + sigf(acc[0]) * tanhfast(acc[2]);
    float h0v = sigf(acc[3]) * tanhfast(c0);
    unsigned v0 = f2h(h0v);
    unsigned v1 = __shfl_down(v0, 16, 64);
    if ((ul & 1) == 0) {
      u64 w = 1ULL | ((u64)v0 << 16) | ((u64)v1 << 32);
      __hip_atomic_store(h0w + (b0 + bt) * 128 + pbase + (ul >> 1), w,
                         __ATOMIC_RELAXED, __HIP_MEMORY_SCOPE_AGENT);
    }
  }

  // --- main loop: interval t computes layer1(t) then layer0(t+1) ---
  for (int t = 0; t < 256; t++) {
    short8 xa0, xa1, xa2, xa3;
    if (t < 255) {
      const unsigned short* xp = seq + ((b0 + bt) * 256 + (t + 1)) * 128 + q8;
      xa0 = *(const short8*)(xp + 0);
      xa1 = *(const short8*)(xp + 32);
      xa2 = *(const short8*)(xp + 64);
      xa3 = *(const short8*)(xp + 96);
    }
    // ---- poll tagged words: h0(t) tag t+1 (buf t&1), h1(t-1) tag t (buf (t+1)&1)
    const u64* q0 = h0w + (t & 1) * 32768 + gb * 2048;
    const u64* q1 = h1w + ((t + 1) & 1) * 32768 + gb * 2048;
    const unsigned short e0 = (unsigned short)(t + 1);
    const unsigned short e1 = (unsigned short)t;
    u64 w0[8], w1[8];
    bool ok0[8], ok1[8];
#pragma unroll
    for (int u = 0; u < 8; u++) {
      ok0[u] = false;
      ok1[u] = false;
    }
    for (;;) {
      bool all_ok = true;
#pragma unroll
      for (int u = 0; u < 8; u++) {
        if (!ok0[u]) {
          w0[u] = __hip_atomic_load(q0 + u * 256 + tid, __ATOMIC_RELAXED,
                                    __HIP_MEMORY_SCOPE_AGENT);
          ok0[u] = ((unsigned short)w0[u] == e0);
        }
        if (!ok1[u]) {
          w1[u] = __hip_atomic_load(q1 + u * 256 + tid, __ATOMIC_RELAXED,
                                    __HIP_MEMORY_SCOPE_AGENT);
          ok1[u] = ((unsigned short)w1[u] == e1);
        }
        all_ok = all_ok & ok0[u] & ok1[u];
      }
      if (__all(all_ok)) break;
    }
    // ---- unpack to LDS (double-buffered) ----
    const int hb = t & 1;
#pragma unroll
    for (int u = 0; u < 8; u++) {
      int g = u * 256 + tid;
      int b = g >> 7, p = g & 127;
      *(unsigned*)&hs0[hb][b * 264 + 2 * p] = (unsigned)(w0[u] >> 16);
      *(unsigned*)&hs1[hb][b * 264 + 2 * p] = (unsigned)(w1[u] >> 16);
    }
    __syncthreads();  // sole barrier per step
    short8 ha[8], hbf[8];
#pragma unroll
    for (int kk = 0; kk < 8; kk++) {
      ha[kk] = *(const short8*)&hs0[hb][bt * 264 + kk * 32 + q8];
      hbf[kk] = *(const short8*)&hs1[hb][bt * 264 + kk * 32 + q8];
    }
    // layer1(t): W1^T @ [h0(t); h1(t-1)]
    f32x4 acc1a = b1v;
    f32x4 acc1b = {0.f, 0.f, 0.f, 0.f};
#pragma unroll
    for (int kk = 0; kk < 8; kk++) {
      acc1a = MFMA(RW(12 + kk), ha[kk], acc1a);
      acc1b = MFMA(RW(20 + kk), hbf[kk], acc1b);
    }
    // layer0(t+1): W0^T @ [x(t+1); h0(t)]
    f32x4 acc0 = b0v;
    if (t < 255) {
      acc0 = MFMA(RW(0), xa0, acc0);
      acc0 = MFMA(RW(1), xa1, acc0);
      acc0 = MFMA(RW(2), xa2, acc0);
      acc0 = MFMA(RW(3), xa3, acc0);
#pragma unroll
      for (int kk = 0; kk < 8; kk++) acc0 = MFMA(RW(4 + kk), ha[kk], acc0);
    }
    // cell1 -> tagged store (tag t+1, buf t&1); fire-and-forget
    {
      float gi = acc1a[0] + acc1b[0], gf = acc1a[1] + acc1b[1];
      float gg = acc1a[2] + acc1b[2], go = acc1a[3] + acc1b[3];
      c1 = sigf(gf) * c1 + sigf(gi) * tanhfast(gg);
      h1v = sigf(go) * tanhfast(c1);
      unsigned v0 = f2h(h1v);
      unsigned v1 = __shfl_down(v0, 16, 64);
      if ((ul & 1) == 0) {
        u64 w = (u64)(unsigned short)(t + 1) | ((u64)v0 << 16) | ((u64)v1 << 32);
        __hip_atomic_store(h1w + (t & 1) * 32768 + (b0 + bt) * 128 + pbase + (ul >> 1),
                           w, __ATOMIC_RELAXED, __HIP_MEMORY_SCOPE_AGENT);
      }
    }
    // cell0 -> tagged store (tag t+2, buf (t+1)&1)
    if (t < 255) {
      c0 = sigf(acc0[1]) * c0 + sigf(acc0[0]) * tanhfast(acc0[2]);
      float h0v = sigf(acc0[3]) * tanhfast(c0);
      unsigned v0 = f2h(h0v);
      unsigned v1 = __shfl_down(v0, 16, 64);
      if ((ul & 1) == 0) {
        u64 w = (u64)(unsigned short)(t + 2) | ((u64)v0 << 16) | ((u64)v1 << 32);
        __hip_atomic_store(
            h0w + ((t + 1) & 1) * 32768 + (b0 + bt) * 128 + pbase + (ul >> 1), w,
            __ATOMIC_RELAXED, __HIP_MEMORY_SCOPE_AGENT);
      }
    }
  }
  hfinal[(b0 + bt) * 256 + sh * 16 + wv * 4 + ul] = h1v;
}

// ---------------- MLP head ----------------
__global__ __launch_bounds__(256, 2) void k_mlp(const float* __restrict__ hfinal,
                                                const float* __restrict__ s,
                                                const float* __restrict__ w1,
                                                const float* __restrict__ b1,
                                                const float* __restrict__ w2,
                                                const float* __restrict__ b2,
                                                const float* __restrict__ wp,
                                                const float* __restrict__ bp,
                                                float* __restrict__ out) {
  __shared__ float feat[257];
  __shared__ float z1[256];
  __shared__ float z2[128];
  const int tid = threadIdx.x, b = blockIdx.x;
  feat[tid] = hfinal[b * 256 + tid];
  if (tid == 0) feat[256] = s[b];
  __syncthreads();
  float a = b1[tid];
  for (int i = 0; i < 257; i++) a += feat[i] * w1[i * 256 + tid];
  z1[tid] = fmaxf(a, 0.f);
  __syncthreads();
  if (tid < 128) {
    float a2 = b2[tid];
    for (int i = 0; i < 256; i++) a2 += z1[i] * w2[i * 128 + tid];
    z2[tid] = fmaxf(a2, 0.f);
  }
  __syncthreads();
  if (tid == 0) {
    float sv = bp[0];
    for (int i = 0; i < 128; i++) sv += z2[i] * wp[i];
    out[b] = fmaxf(sv, 0.f) + log1pf(__expf(-fabsf(sv)));
  }
}

extern "C" void kernel_launch(void* const* d_in, const int* in_sizes, int n_in,
                              void* d_out, int out_size, void* d_ws, size_t ws_size,
                              hipStream_t stream) {
  const float* x = (const float*)d_in[0];
  const float* s = (const float*)d_in[1];
  const float* c1w = (const float*)d_in[2];
  const float* c1b = (const float*)d_in[3];
  const float* bn1g = (const float*)d_in[4];
  const float* bn1b = (const float*)d_in[5];
  const float* c2w = (const float*)d_in[6];
  const float* c2b = (const float*)d_in[7];
  const float* bn2g = (const float*)d_in[8];
  const float* bn2b = (const float*)d_in[9];
  const float* wi0 = (const float*)d_in[10];
  const float* bi0 = (const float*)d_in[11];
  const float* wh0 = (const float*)d_in[12];
  const float* bh0 = (const float*)d_in[13];
  const float* wi1 = (const float*)d_in[14];
  const float* bi1 = (const float*)d_in[15];
  const float* wh1 = (const float*)d_in[16];
  const float* bh1 = (const float*)d_in[17];
  const float* w1 = (const float*)d_in[18];
  const float* b1 = (const float*)d_in[19];
  const float* w2 = (const float*)d_in[20];
  const float* b2 = (const float*)d_in[21];
  const float* wp = (const float*)d_in[22];
  const float* bp = (const float*)d_in[23];

  char* ws = (char*)d_ws;
  float* sc1 = (float*)(ws + OFF_SC1);
  float* sh1 = (float*)(ws + OFF_SH1);
  float* sc2 = (float*)(ws + OFF_SC2);
  float* sh2 = (float*)(ws + OFF_SH2);
  float* b0arr = (float*)(ws + OFF_B0);
  float* b1arr = (float*)(ws + OFF_B1);
  float* part1 = (float*)(ws + OFF_PART1);
  float* part2 = (float*)(ws + OFF_PART2);
  unsigned short* w2f = (unsigned short*)(ws + OFF_W2F);
  unsigned short* wf = (unsigned short*)(ws + OFF_WF);
  unsigned short* seq = (unsigned short*)(ws + OFF_SEQ);
  u64* h0w = (u64*)(ws + OFF_H0W);
  u64* h1w = (u64*)(ws + OFF_H1W);
  float* hf = (float*)(ws + OFF_HF);

  k_init<<<512, 256, 0, stream>>>(h0w);  // zeros h0w + h1w (contiguous 1 MB)
  k_conv1<<<256, 256, 0, stream>>>(x, c1w, c1b, part1);
  k_bn1<<<64, 256, 0, stream>>>(part1, bn1g, bn1b, sc1, sh1);
  k_w2frag<<<160, 256, 0, stream>>>(c2w, w2f);
  k_conv2<<<256, 256, 0, stream>>>(x, c1w, c1b, sc1, sh1, w2f, c2b, seq, part2);
  k_bn2<<<128, 256, 0, stream>>>(part2, bn2g, bn2b, sc2, sh2);
  k_bias<<<4, 256, 0, stream>>>(bi0, bh0, wi0, sh2, bi1, bh1, b0arr, b1arr);
  k_wfrag<<<3584, 256, 0, stream>>>(wi0, wh0, wi1, wh1, sc2, wf);
  k_lstm<<<256, 256, 0, stream>>>(seq, wf, b0arr, b1arr, h0w, h1w, hf);
  k_mlp<<<256, 256, 0, stream>>>(hf, s, w1, b1, w2, b2, wp, bp, (float*)d_out);
}

// Round 7
// 841.207 us; speedup vs baseline: 1.9787x; 1.9787x over previous
//
#include <hip/hip_runtime.h>
#include <hip/hip_bf16.h>
#include <hip/hip_fp16.h>
#include <math.h>

#define EPSV 1e-5f

typedef short short8 __attribute__((ext_vector_type(8)));
typedef float f32x4 __attribute__((ext_vector_type(4)));
typedef unsigned long long u64;

#define MFMA(a, b, c) __builtin_amdgcn_mfma_f32_16x16x32_f16(a, b, c, 0, 0, 0)

// ---------------- ws layout (bytes) ----------------
#define OFF_SC1    8192            // 64 f32
#define OFF_SH1    8448
#define OFF_SC2    8704            // 128 f32
#define OFF_SH2    9216
#define OFF_B0     9728            // 1024 f32 = 4096
#define OFF_B1     13824           // 4096
#define OFF_PART1  17920           // 256*64*2*4 = 131072
#define OFF_PART2  148992          // 256*128*2*4 = 262144
#define OFF_W2F    411136          // 40960 f16 = 81920
#define OFF_WF     493056          // 917504 f16 = 1835008
#define OFF_SEQ    2328064         // 256*256*128*2 = 16777216 (f16 [b][t][c])
#define OFF_H0W    19105280        // 2*16*128*16*8 = 524288 (tagged u64 words)
#define OFF_H1W    19629568        // 524288
#define OFF_HF     20153856        // 256*256*4 = 262144 (f32)
// end 20,416,000

__device__ __forceinline__ unsigned short f2h(float f) {
  return __half_as_ushort(__float2half(f));
}
__device__ __forceinline__ float h2f(unsigned short u) {
  return __half2float(__ushort_as_half(u));
}
__device__ __forceinline__ float sigf(float x) { return 1.f / (1.f + __expf(-x)); }
__device__ __forceinline__ float tanhfast(float x) {
  return 1.f - 2.f / (__expf(2.f * x) + 1.f);
}

// ---------------- init: zero tagged h word buffers (1 MB) ----------------
__global__ void k_init(u64* hz) {
  hz[blockIdx.x * 256 + threadIdx.x] = 0ULL;  // grid 512 -> 131072 u64
}

// ---------------- conv1 + relu + pool4, BN1 partial stats ----------------
__global__ __launch_bounds__(256, 2) void k_conv1(const float* __restrict__ x,
                                                  const float* __restrict__ w1,
                                                  const float* __restrict__ b1,
                                                  float* __restrict__ part1) {
  __shared__ float xs[4104];
  __shared__ float w1s[576];
  __shared__ float b1s[64];
  __shared__ float red[64][4][2];
  const int tid = threadIdx.x, b = blockIdx.x;
  for (int j = tid; j < 4104; j += 256) {
    int p = j - 4;
    xs[j] = (p >= 0 && p < 4096) ? x[b * 4096 + p] : 0.f;
  }
  for (int j = tid; j < 576; j += 256) w1s[j] = w1[j];
  if (tid < 64) b1s[tid] = b1[tid];
  __syncthreads();
  const int c = tid >> 2, lq = tid & 3;
  float wr[9];
#pragma unroll
  for (int k = 0; k < 9; k++) wr[k] = w1s[c * 9 + k];
  const float bb = b1s[c];
  float S = 0.f, SS = 0.f;
  for (int li = 0; li < 256; li++) {
    int l = lq * 256 + li;
    int base = 4 * l;
    float a4 = 0.f;
#pragma unroll
    for (int jj = 0; jj < 4; jj++) {
      float cv = bb;
#pragma unroll
      for (int k = 0; k < 9; k++) cv += xs[base + jj + k] * wr[k];
      a4 += fmaxf(cv, 0.f);
    }
    float y = 0.25f * a4;
    S += y;
    SS += y * y;
  }
  red[c][lq][0] = S;
  red[c][lq][1] = SS;
  __syncthreads();
  if (tid < 64) {
    float s = 0.f, ss = 0.f;
#pragma unroll
    for (int q = 0; q < 4; q++) {
      s += red[tid][q][0];
      ss += red[tid][q][1];
    }
    part1[(b * 64 + tid) * 2 + 0] = s;
    part1[(b * 64 + tid) * 2 + 1] = ss;
  }
}

// ---------------- BN1 finalize ----------------
__global__ void k_bn1(const float* __restrict__ part1, const float* __restrict__ g,
                      const float* __restrict__ bt, float* __restrict__ sc,
                      float* __restrict__ sh) {
  __shared__ float rs[256], rss[256];
  const int c = blockIdx.x, tid = threadIdx.x;
  rs[tid] = part1[(tid * 64 + c) * 2 + 0];
  rss[tid] = part1[(tid * 64 + c) * 2 + 1];
  __syncthreads();
  for (int st = 128; st > 0; st >>= 1) {
    if (tid < st) {
      rs[tid] += rs[tid + st];
      rss[tid] += rss[tid + st];
    }
    __syncthreads();
  }
  if (tid == 0) {
    const float N = 256.f * 1024.f;
    float mean = rs[0] / N;
    float var = rss[0] / N - mean * mean;
    float scale = g[c] * rsqrtf(var + EPSV);
    sc[c] = scale;
    sh[c] = bt[c] - mean * scale;
  }
}

// ---------------- w2 -> MFMA B-fragment layout (f16) ----------------
__global__ void k_w2frag(const float* __restrict__ w2,
                         unsigned short* __restrict__ w2f) {
  int n = blockIdx.x * 256 + threadIdx.x;  // < 40960
  if (n >= 40960) return;
  int e = n & 7, lane = (n >> 3) & 63, ot = (n >> 9) & 7, sc = n >> 12;
  int s = sc >> 1, c2 = sc & 1;
  int o = ot * 16 + (lane & 15);
  int i = c2 * 32 + ((lane >> 4) << 3) + e;
  w2f[n] = f2h(w2[o * 320 + i * 5 + s]);
}

// ---------------- conv2 via MFMA (recomputes conv1+bn1 into LDS y1t) -------
__global__ __launch_bounds__(256, 1) void k_conv2(
    const float* __restrict__ x, const float* __restrict__ w1,
    const float* __restrict__ b1, const float* __restrict__ sc1,
    const float* __restrict__ sh1, const unsigned short* __restrict__ w2f,
    const float* __restrict__ b2, unsigned short* __restrict__ seq,
    float* __restrict__ part2) {
  __shared__ float xs[4104];
  __shared__ unsigned short y1t[1028][66];  // row = l+2, col = i
  __shared__ float w1s[576], b1s[64], s1s[64], h1s[64], b2s[128];
  __shared__ float red[4][2][128];
  const int tid = threadIdx.x, b = blockIdx.x;
  for (int j = tid; j < 4104; j += 256) {
    int p = j - 4;
    xs[j] = (p >= 0 && p < 4096) ? x[b * 4096 + p] : 0.f;
  }
  for (int j = tid; j < 576; j += 256) w1s[j] = w1[j];
  if (tid < 64) {
    b1s[tid] = b1[tid];
    s1s[tid] = sc1[tid];
    h1s[tid] = sh1[tid];
  }
  if (tid < 128) b2s[tid] = b2[tid];
  if (tid < 132) {
    int r4 = tid / 33, c4 = tid % 33;
    int row = (r4 < 2) ? r4 : (1024 + r4);
    ((unsigned int*)&y1t[row][0])[c4] = 0u;
  }
  __syncthreads();
  {
    const int i2 = tid & 31, lg = tid >> 5;
    const int ia = 2 * i2, ib = ia + 1;
    float wra[9], wrb[9];
#pragma unroll
    for (int k = 0; k < 9; k++) {
      wra[k] = w1s[ia * 9 + k];
      wrb[k] = w1s[ib * 9 + k];
    }
    const float bia = b1s[ia], bib = b1s[ib];
    const float sa = s1s[ia], sb = s1s[ib], ha = h1s[ia], hb = h1s[ib];
    for (int j = 0; j < 128; j++) {
      int l = lg * 128 + j;
      float xv[12];
#pragma unroll
      for (int m = 0; m < 12; m++) xv[m] = xs[4 * l + m];
      float aa = 0.f, ab = 0.f;
#pragma unroll
      for (int jj = 0; jj < 4; jj++) {
        float ca = bia, cb = bib;
#pragma unroll
        for (int k = 0; k < 9; k++) {
          float xx = xv[jj + k];
          ca += xx * wra[k];
          cb += xx * wrb[k];
        }
        aa += fmaxf(ca, 0.f);
        ab += fmaxf(cb, 0.f);
      }
      float va = 0.25f * aa * sa + ha;
      float vb = 0.25f * ab * sb + hb;
      unsigned int pk = (unsigned int)f2h(va) | ((unsigned int)f2h(vb) << 16);
      *(unsigned int*)&y1t[l + 2][ia] = pk;
    }
  }
  __syncthreads();
  const int wv = tid >> 6, lane = tid & 63;
  const int colo = lane & 15, rq = lane >> 4;
  float Sa[2][4], SSa[2][4];
#pragma unroll
  for (int a = 0; a < 2; a++)
#pragma unroll
    for (int c = 0; c < 4; c++) {
      Sa[a][c] = 0.f;
      SSa[a][c] = 0.f;
    }
#pragma unroll
  for (int og = 0; og < 2; og++) {
    short8 bf[4][10];
#pragma unroll
    for (int ot = 0; ot < 4; ot++)
#pragma unroll
      for (int sc = 0; sc < 10; sc++)
        bf[ot][sc] = *(const short8*)(w2f + ((sc * 8 + og * 4 + ot) * 64 + lane) * 8);
    for (int ltw = 0; ltw < 16; ltw++) {
      int lt = wv * 16 + ltw;
      int lbase = lt * 16;
      short8 af[10];
#pragma unroll
      for (int s = 0; s < 5; s++)
#pragma unroll
        for (int c2 = 0; c2 < 2; c2++)
          af[s * 2 + c2] =
              *(const short8*)&y1t[lbase + colo + s][c2 * 32 + rq * 8];
#pragma unroll
      for (int ot = 0; ot < 4; ot++) {
        f32x4 acc = {0.f, 0.f, 0.f, 0.f};
#pragma unroll
        for (int sc = 0; sc < 10; sc++)
          acc = MFMA(af[sc], bf[ot][sc], acc);
        int o = (og * 4 + ot) * 16 + colo;
        float bv = b2s[o];
        float s4 = fmaxf(acc[0] + bv, 0.f) + fmaxf(acc[1] + bv, 0.f) +
                   fmaxf(acc[2] + bv, 0.f) + fmaxf(acc[3] + bv, 0.f);
        float y = 0.25f * s4;
        int t_out = lt * 4 + rq;
        seq[(b * 256 + t_out) * 128 + o] = f2h(y);
        Sa[og][ot] += y;
        SSa[og][ot] += y * y;
      }
    }
  }
#pragma unroll
  for (int og = 0; og < 2; og++)
#pragma unroll
    for (int ot = 0; ot < 4; ot++) {
      float sv = Sa[og][ot], ssv = SSa[og][ot];
      sv += __shfl_xor(sv, 16, 64);
      sv += __shfl_xor(sv, 32, 64);
      ssv += __shfl_xor(ssv, 16, 64);
      ssv += __shfl_xor(ssv, 32, 64);
      if (rq == 0) {
        int o = (og * 4 + ot) * 16 + colo;
        red[wv][0][o] = sv;
        red[wv][1][o] = ssv;
      }
    }
  __syncthreads();
  if (tid < 128) {
    float s = red[0][0][tid] + red[1][0][tid] + red[2][0][tid] + red[3][0][tid];
    float ss = red[0][1][tid] + red[1][1][tid] + red[2][1][tid] + red[3][1][tid];
    part2[(b * 128 + tid) * 2 + 0] = s;
    part2[(b * 128 + tid) * 2 + 1] = ss;
  }
}

// ---------------- BN2 finalize ----------------
__global__ void k_bn2(const float* __restrict__ part2, const float* __restrict__ g,
                      const float* __restrict__ bt, float* __restrict__ sc,
                      float* __restrict__ sh) {
  __shared__ float rs[256], rss[256];
  const int o = blockIdx.x, tid = threadIdx.x;
  rs[tid] = part2[(tid * 128 + o) * 2 + 0];
  rss[tid] = part2[(tid * 128 + o) * 2 + 1];
  __syncthreads();
  for (int st = 128; st > 0; st >>= 1) {
    if (tid < st) {
      rs[tid] += rs[tid + st];
      rss[tid] += rss[tid + st];
    }
    __syncthreads();
  }
  if (tid == 0) {
    const float N = 65536.f;
    float mean = rs[0] / N;
    float var = rss[0] / N - mean * mean;
    float scale = g[o] * rsqrtf(var + EPSV);
    sc[o] = scale;
    sh[o] = bt[o] - mean * scale;
  }
}

// ---------------- fold BN2 shift into layer-0 bias ----------------
__global__ void k_bias(const float* __restrict__ bi0, const float* __restrict__ bh0,
                       const float* __restrict__ wi0, const float* __restrict__ sh2,
                       const float* __restrict__ bi1, const float* __restrict__ bh1,
                       float* __restrict__ b0arr, float* __restrict__ b1arr) {
  int g = blockIdx.x * 256 + threadIdx.x;  // < 1024
  float s = bi0[g] + bh0[g];
  for (int k = 0; k < 128; k++) s += sh2[k] * wi0[k * 1024 + g];
  b0arr[g] = s;
  b1arr[g] = bi1[g] + bh1[g];
}

// ---------------- LSTM weights -> A-fragment layout (f16, BN2-scaled) -------
// wf[slot*14336 + ((j)*64 + lane)*8 + e], slot = sh*4+wv
// A[m][k]: m = lane&15 -> gcol = (m&3)*256 + sh*16 + wv*4 + (m>>2)
__global__ void k_wfrag(const float* __restrict__ wi0, const float* __restrict__ wh0,
                        const float* __restrict__ wi1, const float* __restrict__ wh1,
                        const float* __restrict__ sc2,
                        unsigned short* __restrict__ wf) {
  const int slot = blockIdx.x / 56;
  const int idx = (blockIdx.x % 56) * 256 + threadIdx.x;  // < 14336
  const int j = idx >> 9, lane = (idx >> 3) & 63, e = idx & 7;
  const int sh = slot >> 2, wv = slot & 3;
  const int m = lane & 15;
  const int gcol = (m & 3) * 256 + sh * 16 + wv * 4 + (m >> 2);
  float v;
  if (j < 12) {
    int k = j * 32 + ((lane >> 4) << 3) + e;
    v = (k < 128) ? sc2[k] * wi0[k * 1024 + gcol] : wh0[(k - 128) * 1024 + gcol];
  } else {
    int k = (j - 12) * 32 + ((lane >> 4) << 3) + e;
    v = (k < 256) ? wi1[k * 1024 + gcol] : wh1[(k - 256) * 1024 + gcol];
  }
  wf[slot * 14336 + idx] = f2h(v);
}

// ---------------- persistent 2-layer LSTM, tagged coalesced exchange -------
// grid 256 = group gb (blockIdx>>4) x unit-slice sh (blockIdx&15)
// word buffer: [buf][gb][pair p 0..127][batch 0..15] u64
//   word = [tag:16 | h(2p):16 | h(2p+1):16 | 0:16]
__global__ __launch_bounds__(256, 1) void k_lstm(
    const unsigned short* __restrict__ seq, const unsigned short* __restrict__ wf,
    const float* __restrict__ b0arr, const float* __restrict__ b1arr,
    u64* __restrict__ h0w, u64* __restrict__ h1w, float* __restrict__ hfinal) {
  __shared__ unsigned short wlds[4 * 28 * 64 * 8];  // 114688 B
  __shared__ unsigned short hs0[2][16 * 264];       // 16896 B
  __shared__ unsigned short hs1[2][16 * 264];       // 16896 B
  const int tid = threadIdx.x;
  const int gb = blockIdx.x >> 4, sh = blockIdx.x & 15;
  const int b0 = gb * 16;
  const int wv = tid >> 6, lane = tid & 63;
  const int bt = lane & 15;   // batch-local (B-frag col / D col)
  const int ul = lane >> 4;   // unit-local (D row quad / B-frag k-quad)
  const int q8 = ul * 8;

  // ---- stage weight A-fragments into LDS (one copy, fragment-ordered) ----
  {
    const u64* src = (const u64*)(wf + sh * 4 * 14336);
    u64* dst = (u64*)wlds;
    for (int j = tid; j < 14336; j += 256) dst[j] = src[j];
  }
#define LW(j) (*(const short8*)&wlds[(((wv)*28 + (j)) * 64 + lane) * 8])

  f32x4 b0v, b1v;
#pragma unroll
  for (int r = 0; r < 4; r++) {
    int gcol = r * 256 + sh * 16 + wv * 4 + ul;
    b0v[r] = b0arr[gcol];
    b1v[r] = b1arr[gcol];
  }
  float c0 = 0.f, c1 = 0.f, h1v = 0.f;
  const int pidx = (sh * 8 + wv * 2 + (ul >> 1)) * 16 + bt;  // word slot for store
  u64* const st0base = h0w + gb * 2048 + pidx;
  u64* const st1base = h1w + gb * 2048 + pidx;
  __syncthreads();  // weights staged

  // --- prologue: h0(0) = cell(x(0), c=0); store tag 1 into h0w buf0 ---
  {
    const unsigned short* xp = seq + ((b0 + bt) * 256 + 0) * 128 + q8;
    short8 xa0 = *(const short8*)(xp + 0);
    short8 xa1 = *(const short8*)(xp + 32);
    short8 xa2 = *(const short8*)(xp + 64);
    short8 xa3 = *(const short8*)(xp + 96);
    f32x4 acc = b0v;
    acc = MFMA(LW(0), xa0, acc);
    acc = MFMA(LW(1), xa1, acc);
    acc = MFMA(LW(2), xa2, acc);
    acc = MFMA(LW(3), xa3, acc);
    c0 = sigf(acc[1]) * c0 + sigf(acc[0]) * tanhfast(acc[2]);
    float h0v = sigf(acc[3]) * tanhfast(c0);
    unsigned v0 = f2h(h0v);
    unsigned v1 = __shfl_down(v0, 16, 64);
    if ((ul & 1) == 0) {
      u64 w = 1ULL | ((u64)v0 << 16) | ((u64)v1 << 32);
      __hip_atomic_store(st0base, w, __ATOMIC_RELAXED, __HIP_MEMORY_SCOPE_AGENT);
    }
  }

  // --- main loop: interval t computes layer1(t) then layer0(t+1) ---
  for (int t = 0; t < 256; t++) {
    short8 xa0, xa1, xa2, xa3;
    if (t < 255) {
      const unsigned short* xp = seq + ((b0 + bt) * 256 + (t + 1)) * 128 + q8;
      xa0 = *(const short8*)(xp + 0);
      xa1 = *(const short8*)(xp + 32);
      xa2 = *(const short8*)(xp + 64);
      xa3 = *(const short8*)(xp + 96);
    }
    // ---- poll tagged words: h0(t) tag t+1 in buf t&1; h1(t-1) tag t in buf (t+1)&1
    const u64* q0 = h0w + (t & 1) * 32768 + gb * 2048;
    const u64* q1 = h1w + ((t + 1) & 1) * 32768 + gb * 2048;
    const unsigned e0 = (unsigned)(t + 1), e1 = (unsigned)t;
    u64 w0[8], w1[8];
    for (;;) {
      bool ok = true;
#pragma unroll
      for (int u = 0; u < 8; u++) {
        w0[u] = __hip_atomic_load(q0 + u * 256 + tid, __ATOMIC_RELAXED,
                                  __HIP_MEMORY_SCOPE_AGENT);
        w1[u] = __hip_atomic_load(q1 + u * 256 + tid, __ATOMIC_RELAXED,
                                  __HIP_MEMORY_SCOPE_AGENT);
      }
#pragma unroll
      for (int u = 0; u < 8; u++)
        ok = ok & ((unsigned)(unsigned short)w0[u] == e0) &
             ((unsigned)(unsigned short)w1[u] == e1);
      if (__all(ok)) break;
    }
    // ---- unpack to LDS (double-buffered) ----
    const int hb = t & 1;
#pragma unroll
    for (int u = 0; u < 8; u++) {
      int g = u * 256 + tid;
      int bw = g & 15, p = g >> 4;
      *(unsigned*)&hs0[hb][bw * 264 + 2 * p] = (unsigned)(w0[u] >> 16);
      *(unsigned*)&hs1[hb][bw * 264 + 2 * p] = (unsigned)(w1[u] >> 16);
    }
    __syncthreads();  // sole barrier per step
    short8 ha[8], hbf[8];
#pragma unroll
    for (int kk = 0; kk < 8; kk++) {
      ha[kk] = *(const short8*)&hs0[hb][bt * 264 + kk * 32 + q8];
      hbf[kk] = *(const short8*)&hs1[hb][bt * 264 + kk * 32 + q8];
    }
    // layer1(t): W1^T @ [h0(t); h1(t-1)]
    f32x4 acc1a = b1v;
    f32x4 acc1b = {0.f, 0.f, 0.f, 0.f};
#pragma unroll
    for (int kk = 0; kk < 8; kk++) {
      acc1a = MFMA(LW(12 + kk), ha[kk], acc1a);
      acc1b = MFMA(LW(20 + kk), hbf[kk], acc1b);
    }
    // layer0(t+1): W0^T @ [x(t+1); h0(t)]
    f32x4 acc0 = b0v;
    if (t < 255) {
      acc0 = MFMA(LW(0), xa0, acc0);
      acc0 = MFMA(LW(1), xa1, acc0);
      acc0 = MFMA(LW(2), xa2, acc0);
      acc0 = MFMA(LW(3), xa3, acc0);
#pragma unroll
      for (int kk = 0; kk < 8; kk++) acc0 = MFMA(LW(4 + kk), ha[kk], acc0);
    }
    // cell1 (lane-local: reg r = gate) -> tagged store tag t+1, buf t&1
    {
      float gi = acc1a[0] + acc1b[0], gf = acc1a[1] + acc1b[1];
      float gg = acc1a[2] + acc1b[2], go = acc1a[3] + acc1b[3];
      c1 = sigf(gf) * c1 + sigf(gi) * tanhfast(gg);
      h1v = sigf(go) * tanhfast(c1);
      unsigned v0 = f2h(h1v);
      unsigned v1 = __shfl_down(v0, 16, 64);
      if ((ul & 1) == 0) {
        u64 w = (u64)(unsigned short)(t + 1) | ((u64)v0 << 16) | ((u64)v1 << 32);
        __hip_atomic_store(st1base + (t & 1) * 32768, w, __ATOMIC_RELAXED,
                           __HIP_MEMORY_SCOPE_AGENT);
      }
    }
    // cell0 -> tagged store tag t+2, buf (t+1)&1
    if (t < 255) {
      c0 = sigf(acc0[1]) * c0 + sigf(acc0[0]) * tanhfast(acc0[2]);
      float h0v = sigf(acc0[3]) * tanhfast(c0);
      unsigned v0 = f2h(h0v);
      unsigned v1 = __shfl_down(v0, 16, 64);
      if ((ul & 1) == 0) {
        u64 w = (u64)(unsigned short)(t + 2) | ((u64)v0 << 16) | ((u64)v1 << 32);
        __hip_atomic_store(st0base + ((t + 1) & 1) * 32768, w, __ATOMIC_RELAXED,
                           __HIP_MEMORY_SCOPE_AGENT);
      }
    }
  }
  hfinal[(b0 + bt) * 256 + sh * 16 + wv * 4 + ul] = h1v;
}

// ---------------- MLP head ----------------
__global__ __launch_bounds__(256, 2) void k_mlp(const float* __restrict__ hfinal,
                                                const float* __restrict__ s,
                                                const float* __restrict__ w1,
                                                const float* __restrict__ b1,
                                                const float* __restrict__ w2,
                                                const float* __restrict__ b2,
                                                const float* __restrict__ wp,
                                                const float* __restrict__ bp,
                                                float* __restrict__ out) {
  __shared__ float feat[257];
  __shared__ float z1[256];
  __shared__ float z2[128];
  const int tid = threadIdx.x, b = blockIdx.x;
  feat[tid] = hfinal[b * 256 + tid];
  if (tid == 0) feat[256] = s[b];
  __syncthreads();
  float a = b1[tid];
  for (int i = 0; i < 257; i++) a += feat[i] * w1[i * 256 + tid];
  z1[tid] = fmaxf(a, 0.f);
  __syncthreads();
  if (tid < 128) {
    float a2 = b2[tid];
    for (int i = 0; i < 256; i++) a2 += z1[i] * w2[i * 128 + tid];
    z2[tid] = fmaxf(a2, 0.f);
  }
  __syncthreads();
  if (tid == 0) {
    float sv = bp[0];
    for (int i = 0; i < 128; i++) sv += z2[i] * wp[i];
    out[b] = fmaxf(sv, 0.f) + log1pf(__expf(-fabsf(sv)));
  }
}

extern "C" void kernel_launch(void* const* d_in, const int* in_sizes, int n_in,
                              void* d_out, int out_size, void* d_ws, size_t ws_size,
                              hipStream_t stream) {
  const float* x = (const float*)d_in[0];
  const float* s = (const float*)d_in[1];
  const float* c1w = (const float*)d_in[2];
  const float* c1b = (const float*)d_in[3];
  const float* bn1g = (const float*)d_in[4];
  const float* bn1b = (const float*)d_in[5];
  const float* c2w = (const float*)d_in[6];
  const float* c2b = (const float*)d_in[7];
  const float* bn2g = (const float*)d_in[8];
  const float* bn2b = (const float*)d_in[9];
  const float* wi0 = (const float*)d_in[10];
  const float* bi0 = (const float*)d_in[11];
  const float* wh0 = (const float*)d_in[12];
  const float* bh0 = (const float*)d_in[13];
  const float* wi1 = (const float*)d_in[14];
  const float* bi1 = (const float*)d_in[15];
  const float* wh1 = (const float*)d_in[16];
  const float* bh1 = (const float*)d_in[17];
  const float* w1 = (const float*)d_in[18];
  const float* b1 = (const float*)d_in[19];
  const float* w2 = (const float*)d_in[20];
  const float* b2 = (const float*)d_in[21];
  const float* wp = (const float*)d_in[22];
  const float* bp = (const float*)d_in[23];

  char* ws = (char*)d_ws;
  float* sc1 = (float*)(ws + OFF_SC1);
  float* sh1 = (float*)(ws + OFF_SH1);
  float* sc2 = (float*)(ws + OFF_SC2);
  float* sh2 = (float*)(ws + OFF_SH2);
  float* b0arr = (float*)(ws + OFF_B0);
  float* b1arr = (float*)(ws + OFF_B1);
  float* part1 = (float*)(ws + OFF_PART1);
  float* part2 = (float*)(ws + OFF_PART2);
  unsigned short* w2f = (unsigned short*)(ws + OFF_W2F);
  unsigned short* wf = (unsigned short*)(ws + OFF_WF);
  unsigned short* seq = (unsigned short*)(ws + OFF_SEQ);
  u64* h0w = (u64*)(ws + OFF_H0W);
  u64* h1w = (u64*)(ws + OFF_H1W);
  float* hf = (float*)(ws + OFF_HF);

  k_init<<<512, 256, 0, stream>>>(h0w);  // zeros h0w + h1w (contiguous 1 MB)
  k_conv1<<<256, 256, 0, stream>>>(x, c1w, c1b, part1);
  k_bn1<<<64, 256, 0, stream>>>(part1, bn1g, bn1b, sc1, sh1);
  k_w2frag<<<160, 256, 0, stream>>>(c2w, w2f);
  k_conv2<<<256, 256, 0, stream>>>(x, c1w, c1b, sc1, sh1, w2f, c2b, seq, part2);
  k_bn2<<<128, 256, 0, stream>>>(part2, bn2g, bn2b, sc2, sh2);
  k_bias<<<4, 256, 0, stream>>>(bi0, bh0, wi0, sh2, bi1, bh1, b0arr, b1arr);
  k_wfrag<<<3584, 256, 0, stream>>>(wi0, wh0, wi1, wh1, sc2, wf);
  k_lstm<<<256, 256, 0, stream>>>(seq, wf, b0arr, b1arr, h0w, h1w, hf);
  k_mlp<<<256, 256, 0, stream>>>(hf, s, w1, b1, w2, b2, wp, bp, (float*)d_out);
}